// Round 14
// baseline (598.687 us; speedup 1.0000x reference)
//
#include <hip/hip_runtime.h>

// ResidualSimVQ eval forward — R14: R13 (best, 530us) + CB/qf staged in LDS
// via double-buffered global_load_lds DMA (1 barrier/stage, full-stage
// overlap).  Mechanism: per-stage table set was CB 32K + qf 4K + Wn 24K =
// 60K > 32K L1 with 8 drifting waves/CU -> structural L1 thrash on the
// phase-2 sweep.  Moving CB+qf to LDS leaves Wn (24K) alone in L1, and
// phase-2 reads become conflict-free lane-linear ds_read_b128 (16B stride).
// Barrier hazard proof: barrier at top of stage i drains DMA(i) (issued at
// top of stage i-1) and joins all waves past stage i-1's reads of
// buf[(i+1)&1]; DMA(i+1) is issued only after that barrier.  Tile overlays
// buf[1]; DMA(1) is issued after the first loop barrier, when tile reads
// are done.  Everything else identical to R13: barrier-free phases within a
// stage, 4 rows/wave, launch_bounds(256,2) (VGPR-cap law 256/min_waves),
// f32 scoring + exact-f64 global fallback (gap < 0.015), f64 res chain,
// f32 rotation scalars, nt hints on streaming z / z_q.
// commit is wave-uniform -> lane 0's copy IS the wave total (no reduction).
// WRITE_SIZE ~67 MB is the no-spill health metric.

#define NB  16
#define DD  512
#define TT  2048
#define NCB 9
#define CS  1024
#define CD  8
#define KK  9    // CD + 1: slot 8 is the bias b
#define KP  12   // padded f32 row stride (48 B, 16B-aligned rows)
#define NBLK (NB * (TT / 16))   // 2048 k_main blocks
#define GAPTHR 0.015f
#define CBSTG 36864              // per-stage packed CB block: lo|hi|qf

#define WS_WN_OFF  65536                                 // f64 [Wn|b], d-major [i][d][9] (fallback)
#define WS_WNF_OFF (WS_WN_OFF  + (size_t)NCB*DD*KK*8)    // f32 [Wn|b,pad], [i][d][12]
#define WS_Q_OFF   (WS_WNF_OFF + (size_t)NCB*DD*KP*4)    // f64 ||implicit||^2
#define WS_CBP_OFF (WS_Q_OFF   + (size_t)NCB*CS*8)       // packed [i][ lo(16K) | hi(16K) | qf(4K) ]

typedef float vf4 __attribute__((ext_vector_type(4)));   // clang vector for nontemporal builtins

__device__ __forceinline__ void ld_lds16(const void* g, void* l) {
  __builtin_amdgcn_global_load_lds(
      (const __attribute__((address_space(1))) void*)g,
      (__attribute__((address_space(3))) void*)l, 16, 0, 0);
}

__global__ void k_wn(const float* __restrict__ V, const float* __restrict__ g,
                     const float* __restrict__ bp, double* __restrict__ wn,
                     float* __restrict__ wnf) {
  int gid = blockIdx.x * 256 + threadIdx.x;
  if (gid >= NCB * DD) return;
  int i = gid / DD, d = gid % DD;
  const float* vp = V + (size_t)gid * CD;
  double v[CD], s = 0.0;
#pragma unroll
  for (int k = 0; k < CD; k++) { v[k] = (double)vp[k]; s = fma(v[k], v[k], s); }
  double den = fmax(sqrt(s), 1e-12);
  double gg = (double)g[gid];
  double* row = wn + ((size_t)i * DD + d) * KK;
  float* frow = wnf + ((size_t)i * DD + d) * KP;
#pragma unroll
  for (int k = 0; k < CD; k++) {
    double wv = gg * v[k] / den;
    row[k] = wv;
    frow[k] = (float)wv;
  }
  row[CD] = (double)bp[gid];
  frow[CD] = bp[gid];
  frow[9] = 0.0f; frow[10] = 0.0f; frow[11] = 0.0f;
}

__global__ void k_cb(const float* __restrict__ CBp, char* __restrict__ cbp) {
  int gid = blockIdx.x * 256 + threadIdx.x;
  if (gid >= NCB * CS) return;
  int i = gid / CS, c = gid % CS;
  const float4* src = (const float4*)(CBp + (size_t)gid * CD);
  char* base = cbp + (size_t)i * CBSTG;
  ((float4*)base)[c] = src[0];
  ((float4*)(base + 16384))[c] = src[1];
}

__global__ void k_q(const float* __restrict__ CBp, const float* __restrict__ bp,
                    const double* __restrict__ wn,
                    double* __restrict__ q, char* __restrict__ cbp) {
  int wid = blockIdx.x * 4 + (threadIdx.x >> 6);
  int lane = threadIdx.x & 63;
  int i = wid / CS, c = wid % CS;
  const float* cb = CBp + (size_t)(i * CS + c) * CD;
  double cbv[CD];
#pragma unroll
  for (int k = 0; k < CD; k++) cbv[k] = (double)cb[k];
  const double* wnp = wn + (size_t)i * DD * KK;
  const float* bb = bp + (size_t)i * DD;
  double acc = 0.0;
#pragma unroll
  for (int j = 0; j < 8; j++) {
    int d = j * 64 + lane;
    double imp = (double)bb[d];
#pragma unroll
    for (int k = 0; k < CD; k++) imp = fma(cbv[k], wnp[(size_t)d * KK + k], imp);
    acc = fma(imp, imp, acc);
  }
#pragma unroll
  for (int o = 32; o; o >>= 1) acc += __shfl_xor(acc, o, 64);
  if (lane == 0) {
    q[wid] = acc;
    ((float*)(cbp + (size_t)i * CBSTG + 32768))[c] = (float)(0.5 * acc);
  }
}

__launch_bounds__(256, 2)
__global__ void k_main(const float* __restrict__ z, const float* __restrict__ CBp,
                       const double* __restrict__ wn, const float* __restrict__ wnf,
                       const double* __restrict__ qtab, const char* __restrict__ cbp,
                       float* __restrict__ out_zq, float* __restrict__ out_codes,
                       double* __restrict__ partials) {
  __shared__ __align__(16) char sbuf[2 * CBSTG];   // 73728 B (dbuf CB stage)
  __shared__ double cbuf[4];
  float* tile = (float*)(sbuf + CBSTG);            // overlay on buf[1] (34816 <= 36864)

  const int tid = threadIdx.x, lane = tid & 63, w = tid >> 6;
  const int bb = blockIdx.x >> 7, tg = blockIdx.x & 127;
  const int t0 = tg * 16;
  const float* zb = z + (size_t)bb * DD * TT + t0;

  // ---- prologue: stage z (non-temporal), transpose in LDS (tile=buf[1]) ----
#pragma unroll
  for (int m = 0; m < 8; m++) {
    int F = tid + m * 256, d = F >> 2, qq = F & 3;
    const vf4 v = __builtin_nontemporal_load((const vf4*)(zb + (size_t)d * TT + qq * 4));
    tile[d * 17 + qq * 4 + 0] = v.x; tile[d * 17 + qq * 4 + 1] = v.y;
    tile[d * 17 + qq * 4 + 2] = v.z; tile[d * 17 + qq * 4 + 3] = v.w;
  }
  __syncthreads();

  double res[4][8], ns2[4];
#pragma unroll
  for (int r = 0; r < 4; r++) {
    double s = 0.0;
#pragma unroll
    for (int j = 0; j < 8; j++) {
      res[r][j] = (double)tile[(j * 64 + lane) * 17 + (w * 4 + r)];
      s = fma(res[r][j], res[r][j], s);
    }
    ns2[r] = s;
  }
#pragma unroll
  for (int o = 32; o; o >>= 1)
#pragma unroll
    for (int r = 0; r < 4; r++) ns2[r] += __shfl_xor(ns2[r], o, 64);

  // issue DMA(0) into buf[0] (disjoint from tile=buf[1]; no barrier needed)
#pragma unroll
  for (int m = 0; m < 9; m++)
    ld_lds16(cbp + (size_t)w * 9216 + m * 1024 + lane * 16,
             sbuf + w * 9216 + m * 1024);

  double commit = 0.0;

  for (int i = 0; i < NCB; i++) {
    __syncthreads();   // drains DMA(i) (vmcnt 0) + joins waves past stage i-1

    // ---- prefetch stage i+1 packed CB (full-stage overlap) ----
    if (i < NCB - 1) {
      const char* src = cbp + (size_t)(i + 1) * CBSTG;
      char* dst = sbuf + ((i + 1) & 1) * CBSTG;
#pragma unroll
      for (int m = 0; m < 9; m++)
        ld_lds16(src + (size_t)w * 9216 + m * 1024 + lane * 16,
                 dst + w * 9216 + m * 1024);
    }

    const float* wfp = wnf + (size_t)i * DD * KP;
    const float4* lof = (const float4*)(sbuf + (i & 1) * CBSTG);
    const float4* hif = (const float4*)(sbuf + (i & 1) * CBSTG + 16384);
    const float*  qfl = (const float*)(sbuf + (i & 1) * CBSTG + 32768);
    const float* cbbase = CBp + (size_t)i * CS * CD;
    const double* qb = qtab + i * CS;

    // ---- phase 1: pf[r][k] = -(res . [Wn|b]) in f32, one pass, 4 rows ----
    float pf[4][KK];
#pragma unroll
    for (int r = 0; r < 4; r++)
#pragma unroll
      for (int k = 0; k < KK; k++) pf[r][k] = 0.0f;
#pragma unroll
    for (int j = 0; j < 8; j++) {
      const float* row = wfp + (size_t)(j * 64 + lane) * KP;
      const float4 w0 = *(const float4*)(row);
      const float4 w1 = *(const float4*)(row + 4);
      const float  w8 = row[8];
      float rv[4];
#pragma unroll
      for (int r = 0; r < 4; r++) rv[r] = -(float)res[r][j];
#pragma unroll
      for (int r = 0; r < 4; r++) {
        pf[r][0] = fmaf(rv[r], w0.x, pf[r][0]);
        pf[r][1] = fmaf(rv[r], w0.y, pf[r][1]);
        pf[r][2] = fmaf(rv[r], w0.z, pf[r][2]);
        pf[r][3] = fmaf(rv[r], w0.w, pf[r][3]);
        pf[r][4] = fmaf(rv[r], w1.x, pf[r][4]);
        pf[r][5] = fmaf(rv[r], w1.y, pf[r][5]);
        pf[r][6] = fmaf(rv[r], w1.z, pf[r][6]);
        pf[r][7] = fmaf(rv[r], w1.w, pf[r][7]);
        pf[r][8] = fmaf(rv[r], w8,   pf[r][8]);
      }
    }
#pragma unroll
    for (int o = 32; o; o >>= 1)
#pragma unroll
      for (int r = 0; r < 4; r++)
#pragma unroll
        for (int k = 0; k < KK; k++) pf[r][k] += __shfl_xor(pf[r][k], o, 64);

    // ---- phase 2: f32 argmin, one LDS CB sweep, split even/odd chains ----
    float s1a[4], s2a[4], s1b[4], s2b[4];
    int   c1a[4], c1b[4];
#pragma unroll
    for (int r = 0; r < 4; r++) {
      s1a[r] = s2a[r] = s1b[r] = s2b[r] = 3.4e38f;
      c1a[r] = c1b[r] = 0;
    }
#pragma unroll 4
    for (int m = 0; m < 16; m += 2) {
#pragma unroll
      for (int h = 0; h < 2; h++) {
        int c = (m + h) * 64 + lane;
        const float4 c0 = lof[c];
        const float4 cx = hif[c];
        float qv = qfl[c];
#pragma unroll
        for (int r = 0; r < 4; r++) {
          float s = qv;
          s = fmaf(c0.x, pf[r][0], s); s = fmaf(c0.y, pf[r][1], s);
          s = fmaf(c0.z, pf[r][2], s); s = fmaf(c0.w, pf[r][3], s);
          s = fmaf(cx.x, pf[r][4], s); s = fmaf(cx.y, pf[r][5], s);
          s = fmaf(cx.z, pf[r][6], s); s = fmaf(cx.w, pf[r][7], s);
          if (h == 0) {
            if (s < s1a[r]) { s2a[r] = s1a[r]; s1a[r] = s; c1a[r] = c; }
            else            { s2a[r] = fminf(s2a[r], s); }
          } else {
            if (s < s1b[r]) { s2b[r] = s1b[r]; s1b[r] = s; c1b[r] = c; }
            else            { s2b[r] = fminf(s2b[r], s); }
          }
        }
      }
    }
    float s1[4], s2[4]; int c1[4];
#pragma unroll
    for (int r = 0; r < 4; r++) {
      if (s1a[r] < s1b[r] || (s1a[r] == s1b[r] && c1a[r] < c1b[r])) {
        s1[r] = s1a[r]; c1[r] = c1a[r]; s2[r] = fminf(s2a[r], s1b[r]);
      } else {
        s1[r] = s1b[r]; c1[r] = c1b[r]; s2[r] = fminf(s2b[r], s1a[r]);
      }
    }
#pragma unroll
    for (int o = 32; o; o >>= 1) {
#pragma unroll
      for (int r = 0; r < 4; r++) {
        float os1 = __shfl_xor(s1[r], o, 64);
        int   oc1 = __shfl_xor(c1[r], o, 64);
        float os2 = __shfl_xor(s2[r], o, 64);
        float hi = fmaxf(s1[r], os1);
        s2[r] = fminf(fminf(s2[r], os2), hi);
        if (os1 < s1[r] || (os1 == s1[r] && oc1 < c1[r])) { s1[r] = os1; c1[r] = oc1; }
      }
    }

    // ---- per-row: rare exact-f64 fallback (global f64 Wn + CB), scalars ----
    double Ap[4], Cm[4];
    float cbf[4][8];
#pragma unroll
    for (int r = 0; r < 4; r++) {
      if (s2[r] - s1[r] < GAPTHR) {   // wave-uniform, rare
        double pd[KK];
#pragma unroll
        for (int k = 0; k < KK; k++) pd[k] = 0.0;
#pragma unroll
        for (int j = 0; j < 8; j++) {
          const double* wrow = wn + ((size_t)i * DD + j * 64 + lane) * KK;
          double rv = res[r][j];
#pragma unroll
          for (int k = 0; k < KK; k++) pd[k] = fma(rv, wrow[k], pd[k]);
        }
#pragma unroll
        for (int o = 32; o; o >>= 1)
#pragma unroll
          for (int k = 0; k < KK; k++) pd[k] += __shfl_xor(pd[k], o, 64);
        double pm2[8];
#pragma unroll
        for (int k = 0; k < 8; k++) pm2[k] = -2.0 * pd[k];
        double bs = 1e300; int bc = 0;
#pragma unroll 4
        for (int m = 0; m < 16; m++) {
          int c = m * 64 + lane;
          const float* cb2 = cbbase + (size_t)c * CD;
          double s = qb[c];
#pragma unroll
          for (int k = 0; k < 8; k++) s = fma((double)cb2[k], pm2[k], s);
          if (s < bs) { bs = s; bc = c; }
        }
#pragma unroll
        for (int o = 32; o; o >>= 1) {
          double obs = __shfl_xor(bs, o, 64);
          int    obc = __shfl_xor(bc, o, 64);
          if (obs < bs || (obs == bs && obc < bc)) { bs = obs; bc = obc; }
        }
        c1[r] = bc;
      }
      int cu = __builtin_amdgcn_readfirstlane(c1[r]);
      const float4 clo = lof[cu];    // LDS broadcast (uniform addr)
      const float4 chi = hif[cu];
      float cbr[8] = {clo.x, clo.y, clo.z, clo.w, chi.x, chi.y, chi.z, chi.w};
      double pzn = (double)pf[r][8];
#pragma unroll
      for (int k = 0; k < 8; k++) {
        cbf[r][k] = cbr[k];
        pzn = fma((double)cbr[k], (double)pf[r][k], pzn);
      }
      double pz = -pzn;
      double nt2 = qb[cu];
      double n2 = ns2[r];
      // rotation scalars in f32 (A/C need only ~1e-7 rel; decisions already made)
      float n2f = (float)n2, nt2f = (float)nt2, pzf = (float)pz;
      float rnsf = (n2f  > 1e-12f) ? rsqrtf(n2f)  : 1e6f;
      float rntf = (nt2f > 1e-12f) ? rsqrtf(nt2f) : 1e6f;
      float sntf = nt2f * rntf;               // sqrt(nt2)
      float wn2f = n2f * rnsf * rnsf + 2.0f * pzf * rnsf * rntf + nt2f * rntf * rntf;
      float rdwf = (wn2f > 1e-12f) ? rsqrtf(wn2f) : 1e6f;
      float euf = n2f * rnsf;
      float ewf = (n2f * rnsf + pzf * rntf) * rdwf;
      float scalef = sntf * rnsf;
      float Af = scalef * (1.0f - 2.0f * ewf * rdwf * rnsf);
      float Cf = scalef * rntf * 2.0f * (euf - ewf * rdwf);
      commit += n2 - 2.0 * pz + nt2;
      double ap = 1.0 - (double)Af;
      double C  = (double)Cf;
      Ap[r] = ap; Cm[r] = C;
      ns2[r] = ap * ap * n2 - 2.0 * ap * C * pz + C * C * nt2;
      if (lane == 0)
        out_codes[((size_t)bb * NCB + i) * TT + t0 + w * 4 + r] = (float)cu;
    }

    // ---- phase 3: res' = Ap*res - Cm*(b + Wn.cb), f32 imp, one pass ----
#pragma unroll
    for (int j = 0; j < 8; j++) {
      const float* row = wfp + (size_t)(j * 64 + lane) * KP;
      const float4 w0 = *(const float4*)(row);
      const float4 w1 = *(const float4*)(row + 4);
      const float  w8 = row[8];
#pragma unroll
      for (int r = 0; r < 4; r++) {
        float impf = w8;
        impf = fmaf(cbf[r][0], w0.x, impf);
        impf = fmaf(cbf[r][1], w0.y, impf);
        impf = fmaf(cbf[r][2], w0.z, impf);
        impf = fmaf(cbf[r][3], w0.w, impf);
        impf = fmaf(cbf[r][4], w1.x, impf);
        impf = fmaf(cbf[r][5], w1.y, impf);
        impf = fmaf(cbf[r][6], w1.z, impf);
        impf = fmaf(cbf[r][7], w1.w, impf);
        res[r][j] = Ap[r] * res[r][j] - Cm[r] * (double)impf;
      }
    }
  }

  // ---- commit: wave-uniform already; lane 0 holds the wave total ----
  if (lane == 0) cbuf[w] = commit;

  // ---- z_q = z - res_final : transpose via LDS (buf[1]), store (nt) ----
  __syncthreads();   // all waves done with stage 8 (buf[0]); buf[1] free
#pragma unroll
  for (int r = 0; r < 4; r++)
#pragma unroll
    for (int j = 0; j < 8; j++)
      tile[(j * 64 + lane) * 17 + (w * 4 + r)] = (float)res[r][j];
  __syncthreads();   // covers cbuf too
#pragma unroll
  for (int m = 0; m < 8; m++) {
    int F = tid + m * 256, d = F >> 2, qq = F & 3;
    const vf4 v = __builtin_nontemporal_load((const vf4*)(zb + (size_t)d * TT + qq * 4));
    vf4 o;
    o.x = v.x - tile[d * 17 + qq * 4 + 0];
    o.y = v.y - tile[d * 17 + qq * 4 + 1];
    o.z = v.z - tile[d * 17 + qq * 4 + 2];
    o.w = v.w - tile[d * 17 + qq * 4 + 3];
    __builtin_nontemporal_store(o, (vf4*)(out_zq + ((size_t)bb * DD + d) * TT + t0 + qq * 4));
  }
  if (tid == 0)
    partials[blockIdx.x] = cbuf[0] + cbuf[1] + cbuf[2] + cbuf[3];
}

__global__ void k_fin(const double* __restrict__ partials, float* __restrict__ outc) {
  __shared__ double sb[4];
  int tid = threadIdx.x, lane = tid & 63, w = tid >> 6;
  double s = 0.0;
#pragma unroll
  for (int m = 0; m < NBLK / 256; m++) s += partials[tid + m * 256];
#pragma unroll
  for (int o = 32; o; o >>= 1) s += __shfl_xor(s, o, 64);
  if (lane == 0) sb[w] = s;
  __syncthreads();
  if (tid == 0) {
    double tot = sb[0] + sb[1] + sb[2] + sb[3];
    outc[0] = (float)(tot * 1.25 / (double)((size_t)NB * TT * DD));
  }
}

extern "C" void kernel_launch(void* const* d_in, const int* in_sizes, int n_in,
                              void* d_out, int out_size, void* d_ws, size_t ws_size,
                              hipStream_t stream) {
  const float* z  = (const float*)d_in[0];
  const float* V  = (const float*)d_in[1];
  const float* g  = (const float*)d_in[2];
  const float* b  = (const float*)d_in[3];
  const float* CB = (const float*)d_in[4];
  float* out = (float*)d_out;

  double* parts = (double*)d_ws;
  double* wn  = (double*)((char*)d_ws + WS_WN_OFF);
  float*  wnf = (float*)((char*)d_ws + WS_WNF_OFF);
  double* q   = (double*)((char*)d_ws + WS_Q_OFF);
  char*   cbp = (char*)d_ws + WS_CBP_OFF;

  hipLaunchKernelGGL(k_wn, dim3((NCB * DD + 255) / 256), dim3(256), 0, stream,
                     V, g, b, wn, wnf);
  hipLaunchKernelGGL(k_cb, dim3((NCB * CS + 255) / 256), dim3(256), 0, stream, CB, cbp);
  hipLaunchKernelGGL(k_q, dim3((NCB * CS) / 4), dim3(256), 0, stream, CB, b, wn, q, cbp);
  hipLaunchKernelGGL(k_main, dim3(NBLK), dim3(256), 0, stream,
                     z, CB, wn, wnf, q, cbp,
                     out, out + (size_t)NB * DD * TT, parts);
  hipLaunchKernelGGL(k_fin, dim3(1), dim3(256), 0, stream,
                     parts, out + (size_t)NB * DD * TT + (size_t)NB * NCB * TT);
}